// Round 12
// baseline (5317.482 us; speedup 1.0000x reference)
//
#include <hip/hip_runtime.h>
#include <math.h>

// Problem constants
#define BB 32
#define CC 512
#define SS 256      // kv tokens
#define DD 2048     // d_model
#define DIN 512
#define NH 8
#define DHD 64
#define TT 50
#define MM 25
#define HHID 16
#define NSA 512
#define NSO 512
#define NOUT 1000

#define NBLKT 512                  // k_tick grid (2 blocks/CU -> all resident)
#define KT_LDS_FLOATS 15504        // 62,016 B (phase C footprint; A/B alias)

// bf16 helpers (fp32 arithmetic everywhere; bf16 is storage-only)
__device__ __forceinline__ unsigned short f2bf(float f) {
    unsigned u = __float_as_uint(f);
    u += 0x7fffu + ((u >> 16) & 1u);      // round-to-nearest-even
    return (unsigned short)(u >> 16);
}
__device__ __forceinline__ float bf2f(unsigned short s) {
    return __uint_as_float((unsigned)s << 16);
}
__device__ __forceinline__ float blo(unsigned u) {
    return __uint_as_float(u << 16);
}
__device__ __forceinline__ float bhi(unsigned u) {
    return __uint_as_float(u & 0xffff0000u);
}

// Coherent (cross-XCD) write: sc0/sc1 store completing at the MALL. Readers
// use NORMAL cached loads on per-tick-rotated addresses (never L2-cached in
// this launch -> miss -> MALL -> sees the cst data). R10-proven correctness.
__device__ __forceinline__ void cst(float* p, float v) {
    __hip_atomic_store(p, v, __ATOMIC_RELAXED, __HIP_MEMORY_SCOPE_AGENT);
}

// Fence-free grid barrier (monotone counter; no cache maintenance).
__device__ __forceinline__ void gsync(unsigned* __restrict__ ctr, unsigned target)
{
    __threadfence_block();
    __syncthreads();
    if (threadIdx.x == 0) {
        __hip_atomic_fetch_add(ctr, 1u, __ATOMIC_RELAXED, __HIP_MEMORY_SCOPE_AGENT);
        while (__hip_atomic_load(ctr, __ATOMIC_RELAXED, __HIP_MEMORY_SCOPE_AGENT) < target)
            __builtin_amdgcn_s_sleep(4);
        asm volatile("" ::: "memory");
    }
    __syncthreads();
}

// ---------------------------------------------------------------------------
// Init: barrier, decays, sync states, trace0
// ---------------------------------------------------------------------------
__global__ void init_kernel(const float* __restrict__ dec_a, const float* __restrict__ dec_o,
                            const float* __restrict__ start_act, const float* __restrict__ start_trace,
                            const int* __restrict__ idx_lo, const int* __restrict__ idx_ro,
                            unsigned* __restrict__ bar,
                            float* __restrict__ r_a, float* __restrict__ r_o,
                            float* __restrict__ a_a, float* __restrict__ b_a,
                            float* __restrict__ a_o, float* __restrict__ b_o,
                            float* __restrict__ trace)
{
    int i = blockIdx.x * 256 + threadIdx.x;
    if (i < 16) bar[i] = 0u;
    if (i < 512) {
        r_a[i] = expf(-fminf(fmaxf(dec_a[i], 0.f), 15.f));
        r_o[i] = expf(-fminf(fmaxf(dec_o[i], 0.f), 15.f));
    }
    if (i < BB * NSA) {
        a_a[i] = 0.f; b_a[i] = 0.f;
        int j = i & 511;
        a_o[i] = start_act[idx_lo[j]] * start_act[idx_ro[j]];
        b_o[i] = 1.f;
    }
    if (i < BB * MM * DD) {
        int rem = i % (MM * DD);
        int m = rem / DD, d = rem % DD;
        trace[i] = start_trace[d * MM + m];   // start_trace is (D,M)
    }
}

// ---------------------------------------------------------------------------
// Generic 64x64 tiled GEMM. SMODE 0: fp32 row-major+bias. SMODE 3: bf16
// khT layout (B,H,DH,S). SMODE 4: bf16 vh layout (B,H,S,DH).
// ---------------------------------------------------------------------------
template<int AMODE, int SMODE>
__global__ void gemm64(const float* __restrict__ A, const float* __restrict__ Bm,
                       const float* __restrict__ bias, float* __restrict__ Cm,
                       int Mdim, int Ndim, int Kdim)
{
    __shared__ float As[16 * 65];
    __shared__ float Bs[16 * 64];
    int row0 = blockIdx.x * 64;
    int col0 = blockIdx.y * 64;
    int t = threadIdx.x;
    int tx = t & 15, ty = t >> 4;
    float acc[4][4] = {};
    for (int k0 = 0; k0 < Kdim; k0 += 16) {
        if (AMODE == 0) {
            for (int i = t; i < 1024; i += 256) {
                int kk = i & 15, r = i >> 4;
                As[kk * 65 + r] = A[(size_t)(row0 + r) * Kdim + k0 + kk];
            }
        } else {
            int b = row0 / SS, s0 = row0 % SS;
            for (int i = t; i < 1024; i += 256) {
                int r = i & 63, kk = i >> 6;
                As[kk * 65 + r] = A[((size_t)b * CC + k0 + kk) * SS + s0 + r];
            }
        }
        for (int i = t; i < 1024; i += 256) {
            int c = i & 63, kk = i >> 6;
            Bs[kk * 64 + c] = Bm[(size_t)(k0 + kk) * Ndim + col0 + c];
        }
        __syncthreads();
        #pragma unroll
        for (int kk = 0; kk < 16; ++kk) {
            float a[4], bb[4];
            #pragma unroll
            for (int i = 0; i < 4; i++) a[i] = As[kk * 65 + ty * 4 + i];
            #pragma unroll
            for (int j = 0; j < 4; j++) bb[j] = Bs[kk * 64 + tx * 4 + j];
            #pragma unroll
            for (int i = 0; i < 4; i++)
                #pragma unroll
                for (int j = 0; j < 4; j++) acc[i][j] += a[i] * bb[j];
        }
        __syncthreads();
    }
    #pragma unroll
    for (int i = 0; i < 4; i++)
        #pragma unroll
        for (int j = 0; j < 4; j++) {
            int row = row0 + ty * 4 + i, col = col0 + tx * 4 + j;
            float v = acc[i][j] + (bias ? bias[col] : 0.f);
            if (SMODE == 0) {
                Cm[(size_t)row * Ndim + col] = v;
            } else if (SMODE == 3) {
                int b = row / SS, s = row % SS, h = col >> 6, dh = col & 63;
                ((unsigned short*)Cm)[(((size_t)b * NH + h) * DHD + dh) * SS + s] = f2bf(v);
            } else if (SMODE == 4) {
                int b = row / SS, s = row % SS, h = col >> 6, dh = col & 63;
                ((unsigned short*)Cm)[(((size_t)b * NH + h) * SS + s) * DHD + dh] = f2bf(v);
            }
        }
}

// LayerNorm over rows of 512 (in place)
__global__ void ln_rows(float* __restrict__ buf, const float* __restrict__ g,
                        const float* __restrict__ bta)
{
    int row = blockIdx.x, t = threadIdx.x;
    __shared__ float red[256];
    float v0 = buf[(size_t)row * 512 + t];
    float v1 = buf[(size_t)row * 512 + 256 + t];
    red[t] = v0 + v1; __syncthreads();
    for (int off = 128; off; off >>= 1) { if (t < off) red[t] += red[t + off]; __syncthreads(); }
    float mu = red[0] * (1.f / 512.f); __syncthreads();
    float d0 = v0 - mu, d1 = v1 - mu;
    red[t] = d0 * d0 + d1 * d1; __syncthreads();
    for (int off = 128; off; off >>= 1) { if (t < off) red[t] += red[t + off]; __syncthreads(); }
    float rstd = 1.f / sqrtf(red[0] * (1.f / 512.f) + 1e-5f);
    buf[(size_t)row * 512 + t]       = d0 * rstd * g[t] + bta[t];
    buf[(size_t)row * 512 + 256 + t] = d1 * rstd * g[t + 256] + bta[t + 256];
}

__global__ void bqq_kernel(const float* __restrict__ q_b, const float* __restrict__ Wq,
                           const float* __restrict__ bq, float* __restrict__ bqq)
{
    int c = blockIdx.x * 256 + threadIdx.x;
    if (c >= 512) return;
    float acc = bq[c];
    for (int k = 0; k < 512; k++) acc += q_b[k] * Wq[k * 512 + c];
    bqq[c] = acc;
}

__global__ void bias2_kernel(const float* __restrict__ bo, const float* __restrict__ syn_w,
                             const float* __restrict__ syn_b, float* __restrict__ bias2)
{
    int c = blockIdx.x * 256 + threadIdx.x;
    if (c >= 4096) return;
    float acc = syn_b[c];
    for (int k = 0; k < 512; k++) acc += bo[k] * syn_w[(size_t)k * 4096 + c];
    bias2[c] = acc;
}

// Build WTh[c][k] = bf16(Wcomb[k][c]) (Wcomb = [W2;syn_w]).
__global__ void wt_build(const float* __restrict__ W2, const float* __restrict__ syn_w,
                         unsigned short* __restrict__ WTh)
{
    __shared__ float tile[32][33];
    int k0 = blockIdx.x * 32, c0 = blockIdx.y * 32;
    int t = threadIdx.x;
    int col = t & 31, rq = t >> 5;
    #pragma unroll
    for (int q = 0; q < 4; ++q) {
        int kk = q * 8 + rq;
        int k = k0 + kk;
        const float* src = (k < 512 ? W2 : syn_w) + (size_t)k * 4096 + c0;
        tile[kk][col] = src[col];
    }
    __syncthreads();
    #pragma unroll
    for (int q = 0; q < 4; ++q) {
        int cc = q * 8 + rq;
        WTh[(size_t)(c0 + cc) * 2560 + k0 + col] = f2bf(tile[col][cc]);
    }
}

// Convert nlm_w1 to bf16.
__global__ void conv_w1(const float* __restrict__ w1, unsigned short* __restrict__ w1h)
{
    int i = blockIdx.x * 256 + threadIdx.x;
    if (i < 25 * 32 * DD) w1h[i] = f2bf(w1[i]);
}

__global__ void act0_kernel(const float* __restrict__ start_act, float* __restrict__ act0slot)
{
    int i = blockIdx.x * 256 + threadIdx.x;
    if (i < BB * DD) act0slot[i] = start_act[i & (DD - 1)];
}

__global__ void pad_outw(const float* __restrict__ out_w, const float* __restrict__ out_b,
                         float* __restrict__ out_wp, float* __restrict__ out_bp)
{
    int i = blockIdx.x * 256 + threadIdx.x;
    if (i < 512 * 1024) {
        int r = i >> 10, c = i & 1023;
        out_wp[i] = (c < 1000) ? out_w[r * 1000 + c] : 0.f;
    }
    if (i < 1024) out_bp[i] = (i < 1000) ? out_b[i] : 0.f;
}

// ---------------------------------------------------------------------------
// k_tick: one launch per tick. Grid 512 x 256, 62KB LDS (2 blocks/CU, all
// resident). Phase A (blk<256): sync_a+qh+attn -> obufR[t] (cst). Barrier.
// Phase B (all): synapse GEMM + GLU -> glR[t], partR[t] (cst). Barrier.
// Phase C (all): LN-finish + NLM -> trace, act_{t+1} (normal stores; next
// launch reads across the kernel boundary).
// ---------------------------------------------------------------------------
__global__ __launch_bounds__(256) void k_tick(
    const float* __restrict__ act_t, float* __restrict__ act_n,
    const int* __restrict__ la, const int* __restrict__ ra,
    const float* __restrict__ r_a,
    const float* __restrict__ aold, const float* __restrict__ bold,
    float* __restrict__ anew, float* __restrict__ bnew,
    const float* __restrict__ Wqq, const float* __restrict__ bqq,
    const unsigned short* __restrict__ khTh, const unsigned short* __restrict__ vhh,
    const unsigned short* __restrict__ WTh, const float* __restrict__ bias2,
    const float* __restrict__ g, const float* __restrict__ bta,
    float* __restrict__ trace,
    const unsigned short* __restrict__ w1h, const float* __restrict__ b1,
    const float* __restrict__ w2, const float* __restrict__ b2,
    float* __restrict__ obuf_t, float* __restrict__ gl_t, float* __restrict__ part_t,
    unsigned* __restrict__ bar, int t_iter)
{
    extern __shared__ float lds[];
    const int blk = blockIdx.x;
    const int tid = threadIdx.x;
    const unsigned base = (unsigned)t_iter * (2u * NBLKT);

    // ================= Phase A: attention front (blocks 0..255) ============
    if (blk < 256) {
        float* sa  = lds;           // 512
        float* qp  = lds + 512;     // 256
        float* qs  = lds + 768;     // 64
        float* ps  = lds + 832;     // 256
        float* red = lds + 1088;    // 256
        int b = blk >> 3, h = blk & 7;
        const float* actb = act_t + b * DD;
        for (int j = tid; j < 512; j += 256) {
            float p = actb[la[j]] * actb[ra[j]];
            float r = r_a[j];
            float aa = r * aold[b * 512 + j] + p;
            float bb = r * bold[b * 512 + j] + 1.f;
            sa[j] = aa / sqrtf(bb);
            if (h == 0) { anew[b * 512 + j] = aa; bnew[b * 512 + j] = bb; }
        }
        __syncthreads();
        {
            int cl = tid & 63, q = tid >> 6;
            const float* wcol = Wqq + h * 64 + cl;
            float acc = 0.f;
            #pragma unroll 8
            for (int k = q * 128; k < q * 128 + 128; ++k)
                acc += sa[k] * wcol[k * 512];
            qp[tid] = acc;
        }
        __syncthreads();
        if (tid < 64)
            qs[tid] = qp[tid] + qp[tid + 64] + qp[tid + 128] + qp[tid + 192] + bqq[h * 64 + tid];
        __syncthreads();
        const unsigned short* kb = khTh + (size_t)blk * 64 * 256;   // [dh][s]
        float sc = 0.f;
        #pragma unroll 8
        for (int dh = 0; dh < 64; ++dh) sc += qs[dh] * bf2f(kb[dh * 256 + tid]);
        sc *= 0.125f;
        red[tid] = sc; __syncthreads();
        for (int off = 128; off; off >>= 1) { if (tid < off) red[tid] = fmaxf(red[tid], red[tid + off]); __syncthreads(); }
        float mx = red[0]; __syncthreads();
        float e = expf(sc - mx);
        red[tid] = e; __syncthreads();
        for (int off = 128; off; off >>= 1) { if (tid < off) red[tid] += red[tid + off]; __syncthreads(); }
        float inv = 1.f / red[0];
        ps[tid] = e * inv;
        __syncthreads();
        int dh = tid & 63, ch = tid >> 6;
        const unsigned short* vb = vhh + (size_t)blk * 256 * 64;    // [s][dh]
        float acc = 0.f;
        for (int s = ch * 64; s < ch * 64 + 64; ++s) acc += ps[s] * bf2f(vb[s * 64 + dh]);
        red[tid] = acc; __syncthreads();
        if (tid < 128) red[tid] += red[tid + 128];
        __syncthreads();
        if (tid < 64) cst(&obuf_t[b * 512 + h * 64 + tid], red[tid] + red[tid + 64]);
    }
    gsync(bar, base + NBLKT);

    // ================= Phase B: synapse GEMM + GLU + LN partials ===========
    {
        float* As = lds;   // 2*32*160 = 10240 floats, swizzled
        int kh = tid >> 7;            // 0..1
        int cpair = (tid >> 5) & 3;   // 0..3
        int r = tid & 31;
        int c = blk * 4 + cpair;
        const unsigned short* wta = WTh + (size_t)c * 2560 + kh * 1280;
        const unsigned short* wtb = WTh + (size_t)(c + 2048) * 2560 + kh * 1280;
        float acc_a = 0.f, acc_b = 0.f;
        for (int ri = 0; ri < 8; ++ri) {
            __syncthreads();
            #pragma unroll
            for (int q = 0; q < 10; ++q) {
                int i = tid + q * 256;        // 0..2559
                int hh = i / 1280;
                int rem = i - hh * 1280;
                int rr = rem / 40, kg = rem - (rem / 40) * 40;
                int k = hh * 1280 + ri * 160 + kg * 4;
                float4 v;
                if (k < 512) v = *(const float4*)(obuf_t + rr * 512 + k);
                else         v = *(const float4*)(act_t + rr * 2048 + (k - 512));
                *(float4*)(As + hh * 5120 + rr * 160 + ((kg ^ (rr & 7)) << 2)) = v;
            }
            __syncthreads();
            const float* Ar = As + kh * 5120 + r * 160;
            const unsigned short* wtaa = wta + ri * 160;
            const unsigned short* wtbb = wtb + ri * 160;
            int sw = r & 7;
            #pragma unroll 4
            for (int kc = 0; kc < 20; ++kc) {
                uint4 wa = *(const uint4*)(wtaa + kc * 8);   // 8 bf16 weights
                uint4 wb = *(const uint4*)(wtbb + kc * 8);
                float4 a0 = *(const float4*)(Ar + (((2 * kc) ^ sw) << 2));
                float4 a1 = *(const float4*)(Ar + (((2 * kc + 1) ^ sw) << 2));
                acc_a += a0.x * blo(wa.x) + a0.y * bhi(wa.x) + a0.z * blo(wa.y) + a0.w * bhi(wa.y)
                       + a1.x * blo(wa.z) + a1.y * bhi(wa.z) + a1.z * blo(wa.w) + a1.w * bhi(wa.w);
                acc_b += a0.x * blo(wb.x) + a0.y * bhi(wb.x) + a0.z * blo(wb.y) + a0.w * bhi(wb.y)
                       + a1.x * blo(wb.z) + a1.y * bhi(wb.z) + a1.z * blo(wb.w) + a1.w * bhi(wb.w);
            }
        }
        __syncthreads();
        float* red_a = lds;            // 128
        float* red_b = lds + 128;      // 128
        float* gls   = lds + 256;      // 128
        float* gl2s  = lds + 384;      // 128
        if (kh == 1) {
            red_a[cpair * 32 + r] = acc_a;
            red_b[cpair * 32 + r] = acc_b;
        }
        __syncthreads();
        if (kh == 0) {
            float ua = acc_a + red_a[cpair * 32 + r] + bias2[c];
            float ub = acc_b + red_b[cpair * 32 + r] + bias2[c + 2048];
            float gl = ua * (1.f / (1.f + expf(-ub)));
            cst(&gl_t[c * 32 + r], gl);
            gls[cpair * 32 + r] = gl;
            gl2s[cpair * 32 + r] = gl * gl;
        }
        __syncthreads();
        if (tid < 32) {
            float s = 0.f, s2 = 0.f;
            #pragma unroll
            for (int cp = 0; cp < 4; ++cp) { s += gls[cp * 32 + tid]; s2 += gl2s[cp * 32 + tid]; }
            cst(&part_t[blk * 64 + tid * 2], s);
            cst(&part_t[blk * 64 + tid * 2 + 1], s2);
        }
    }
    gsync(bar, base + 2 * NBLKT);

    // ================= Phase C: LN-finish + per-neuron MLP =================
    {
        float* wlds  = lds;             // 12800: [m*32+h][16 d_l]
        float* cross = lds + 12800;     // 2176
        float* r1 = lds + 14976;        // 256
        float* r2 = lds + 15232;        // 256
        float* sm = lds + 15488;        // 16
        int dtile = blk & 127, bgrp = blk >> 7;
        int d0 = dtile * 16, b0 = bgrp * 8;
        int hh = tid >> 7;
        int b_l = (tid >> 4) & 7;
        int d_l = tid & 15;
        int b = b0 + b_l, d = d0 + d_l;

        // stage w1 slice from bf16: 12800 floats, 50 per thread
        for (int q = 0; q < 50; ++q) {
            int i = tid + q * 256;
            wlds[i] = bf2f(w1h[(size_t)(i >> 4) * 2048 + d0 + (i & 15)]);
        }
        // LN stats (reads part_t: rotated address, normal loads -> MALL)
        {
            int bb = tid >> 5, j = tid & 31;
            int bstat = b0 + bb;
            float s = 0.f, s2 = 0.f;
            #pragma unroll
            for (int q = 0; q < 16; ++q) {
                int kblk = j + 32 * q;
                s  += part_t[kblk * 64 + bstat * 2];
                s2 += part_t[kblk * 64 + bstat * 2 + 1];
            }
            r1[tid] = s; r2[tid] = s2;
            __syncthreads();
            for (int off = 16; off; off >>= 1) {
                if (j < off) { r1[tid] += r1[tid + off]; r2[tid] += r2[tid + off]; }
                __syncthreads();
            }
            if (j == 0) {
                float mu = r1[tid] * (1.f / 2048.f);
                float var = r2[tid] * (1.f / 2048.f) - mu * mu;
                sm[bb * 2] = mu;
                sm[bb * 2 + 1] = 1.f / sqrtf(var + 1e-5f);
            }
            __syncthreads();
        }
        float mu = sm[b_l * 2], rstd = sm[b_l * 2 + 1];
        float gl = gl_t[d * 32 + b];
        float nv = (gl - mu) * rstd * g[d] + bta[d];
        int newrow = t_iter % MM;
        if (hh == 0) trace[((size_t)b * MM + newrow) * DD + d] = nv;

        float hp[16];
        {
            const float* b1d = b1 + d * 32 + hh * 16;
            #pragma unroll
            for (int h = 0; h < 16; h++) hp[h] = b1d[h];
        }
        const float* trb = trace + (size_t)b * MM * DD + d;
        for (int m = 0; m < 24; m++) {
            int mph = (t_iter + 1 + m) % 25;
            float tv = trb[(size_t)mph * DD];
            const float* wm = wlds + (m * 32 + hh * 16) * 16 + d_l;
            #pragma unroll
            for (int h = 0; h < 16; h++) hp[h] += tv * wm[h * 16];
        }
        {
            const float* wm = wlds + (24 * 32 + hh * 16) * 16 + d_l;
            #pragma unroll
            for (int h = 0; h < 16; h++) hp[h] += nv * wm[h * 16];
        }
        if (hh == 1) {
            float* cx = cross + (b_l * 16 + d_l) * 17;
            #pragma unroll
            for (int h = 0; h < 16; h++) cx[h] = hp[h];
        }
        __syncthreads();
        if (hh == 0) {
            const float* cx = cross + (b_l * 16 + d_l) * 17;
            float o0 = b2[d * 2], o1 = b2[d * 2 + 1];
            #pragma unroll
            for (int h = 0; h < 16; h++) {
                float hv = hp[h] * (1.f / (1.f + expf(-cx[h])));
                o0 += hv * w2[((size_t)h * 2) * DD + d];
                o1 += hv * w2[((size_t)h * 2 + 1) * DD + d];
            }
            act_n[b * DD + d] = o0 * (1.f / (1.f + expf(-o1)));
        }
    }
}

// ---------------------------------------------------------------------------
// Post: sync_o linear recurrence over all 50 ticks. Thread = (b,j).
// ---------------------------------------------------------------------------
__global__ __launch_bounds__(256) void k_syncscan(
    const float* __restrict__ acthist, const int* __restrict__ lo, const int* __restrict__ ro,
    const float* __restrict__ r_o,
    const float* __restrict__ a_o0, const float* __restrict__ b_o0,
    float* __restrict__ so_hist, float* __restrict__ out_sync)
{
    int idx = blockIdx.x * 256 + threadIdx.x;   // 0..16383
    int b = idx >> 9, j = idx & 511;
    float aa = a_o0[idx], bb = b_o0[idx];
    float rr = r_o[j];
    int il = lo[j], ir = ro[j];
    const float* ah = acthist + (size_t)(BB * DD) + b * DD;
    float s = 0.f;
    for (int t = 0; t < TT; ++t) {
        float p = ah[il] * ah[ir];
        aa = rr * aa + p;
        bb = rr * bb + 1.f;
        s = aa / sqrtf(bb);
        so_hist[(size_t)t * (BB * 512) + idx] = s;
        ah += BB * DD;
    }
    out_sync[idx] = s;
}

// ---------------------------------------------------------------------------
// Post: certainty + prediction write-out for ALL ticks. Grid 1600 = (t, b).
// ---------------------------------------------------------------------------
__global__ __launch_bounds__(256) void k6_cert(
    const float* __restrict__ predt, float* __restrict__ d_out)
{
    int t_iter = blockIdx.x >> 5, b = blockIdx.x & 31, t = threadIdx.x;
    __shared__ float red[256];
    const float* pr = predt + ((size_t)t_iter * 32 + b) * 1024;
    float pv[4];
    float mx = -1e30f;
    #pragma unroll
    for (int ii = 0; ii < 4; ++ii) {
        int c = t + ii * 256;
        float v = -1e30f;
        if (c < 1000) {
            v = pr[c];
            d_out[(size_t)b * NOUT * TT + (size_t)c * TT + t_iter] = v;
        }
        pv[ii] = v;
        mx = fmaxf(mx, v);
    }
    red[t] = mx; __syncthreads();
    for (int off = 128; off; off >>= 1) { if (t < off) red[t] = fmaxf(red[t], red[t + off]); __syncthreads(); }
    mx = red[0]; __syncthreads();
    float s1 = 0.f, s2 = 0.f;
    #pragma unroll
    for (int ii = 0; ii < 4; ++ii) {
        int c = t + ii * 256;
        if (c < 1000) { float xx = pv[ii] - mx; float e = expf(xx); s1 += e; s2 += e * xx; }
    }
    red[t] = s1; __syncthreads();
    for (int off = 128; off; off >>= 1) { if (t < off) red[t] += red[t + off]; __syncthreads(); }
    s1 = red[0]; __syncthreads();
    red[t] = s2; __syncthreads();
    for (int off = 128; off; off >>= 1) { if (t < off) red[t] += red[t + off]; __syncthreads(); }
    s2 = red[0];
    if (t == 0) {
        float ne = -(s2 / s1 - logf(s1)) * (1.f / logf(1000.f));
        size_t base = (size_t)BB * NOUT * TT + (size_t)b * 2 * TT + t_iter;
        d_out[base] = ne;
        d_out[base + TT] = 1.f - ne;
    }
}

// ---------------------------------------------------------------------------
extern "C" void kernel_launch(void* const* d_in, const int* in_sizes, int n_in,
                              void* d_out, int out_size, void* d_ws, size_t ws_size,
                              hipStream_t stream)
{
    const float* x        = (const float*)d_in[0];
    const float* kv_w     = (const float*)d_in[1];
    const float* kv_b     = (const float*)d_in[2];
    const float* ln_kv_g  = (const float*)d_in[3];
    const float* ln_kv_b  = (const float*)d_in[4];
    const float* q_w      = (const float*)d_in[5];
    const float* q_b      = (const float*)d_in[6];
    const float* Wq       = (const float*)d_in[7];
    const float* bq       = (const float*)d_in[8];
    const float* Wk       = (const float*)d_in[9];
    const float* bk       = (const float*)d_in[10];
    const float* Wv       = (const float*)d_in[11];
    const float* bv       = (const float*)d_in[12];
    const float* Wo       = (const float*)d_in[13];
    const float* bo       = (const float*)d_in[14];
    const float* syn_w    = (const float*)d_in[15];
    const float* syn_b    = (const float*)d_in[16];
    const float* ln_syn_g = (const float*)d_in[17];
    const float* ln_syn_b = (const float*)d_in[18];
    const float* nlm_w1   = (const float*)d_in[19];
    const float* nlm_b1   = (const float*)d_in[20];
    const float* nlm_w2   = (const float*)d_in[21];
    const float* nlm_b2   = (const float*)d_in[22];
    const float* out_w    = (const float*)d_in[23];
    const float* out_b    = (const float*)d_in[24];
    const float* dec_a    = (const float*)d_in[25];
    const float* dec_o    = (const float*)d_in[26];
    const float* start_tr = (const float*)d_in[27];
    const float* start_ac = (const float*)d_in[28];
    const int*   idx_la   = (const int*)d_in[29];
    const int*   idx_ra   = (const int*)d_in[30];
    const int*   idx_lo   = (const int*)d_in[31];
    const int*   idx_ro   = (const int*)d_in[32];
    float* out = (float*)d_out;

    // workspace carve: bar (256B) then floats.
    unsigned* bar = (unsigned*)d_ws;
    float* w = (float*)d_ws + 64;
    float* kvbuf = w;            w += (size_t)8192 * 512;     // acthist alias
    float* bigA  = w;            w += (size_t)8192 * 512;     // glR; out_wp/bp post-loop
    float* bigB  = w;            w += (size_t)8192 * 512;     // obufR+partR; so_hist/predt post
    float* Wqq   = w;            w += (size_t)512 * 512;
    float* bqq   = w;            w += 512;
    float* W2    = w;            w += (size_t)512 * 4096;
    float* bias2 = w;            w += 4096;
    float* r_a   = w;            w += 512;
    float* r_o   = w;            w += 512;
    float* a_a   = w;            w += 2 * BB * NSA;           // ping-pong
    float* b_a   = w;            w += 2 * BB * NSA;
    float* a_o   = w;            w += BB * NSO;
    float* b_o   = w;            w += BB * NSO;
    float* trace = w;            w += (size_t)BB * MM * DD;
    unsigned short* WTh  = (unsigned short*)w;  w += (size_t)4096 * 2560 / 2;  // 21MB bf16
    unsigned short* khTh = (unsigned short*)w;  w += (size_t)8192 * 512 / 2;   // 8.4MB
    unsigned short* vhh  = (unsigned short*)w;  w += (size_t)8192 * 512 / 2;
    unsigned short* w1h  = (unsigned short*)w;  w += (size_t)25 * 32 * DD / 2;

    float* acthist = kvbuf;                    // 51*65536 = 3.34M floats
    float* glR     = bigA;                     // 50*65536 = 3.28M floats
    float* out_wp  = bigA + 3276800;           // 524,289 floats (post-loop)
    float* out_bp  = out_wp + 524288;
    float* obufR   = bigB;                     // 50*16384 = 819,200
    float* partR   = bigB + 819200;            // 50*32768 = 1,638,400
    float* so_hist = bigB;                     // post-loop (obufR dead)
    float* predt   = bigB + 819200;            // post-loop (partR dead)

    // ---- precompute ----
    init_kernel<<<6400, 256, 0, stream>>>(dec_a, dec_o, start_ac, start_tr, idx_lo, idx_ro,
                                          bar, r_a, r_o, a_a, b_a, a_o, b_o, trace);
    gemm64<1, 0><<<dim3(128, 8), 256, 0, stream>>>(x, kv_w, kv_b, kvbuf, 8192, 512, 512);
    ln_rows<<<8192, 256, 0, stream>>>(kvbuf, ln_kv_g, ln_kv_b);
    gemm64<0, 3><<<dim3(128, 8), 256, 0, stream>>>(kvbuf, Wk, bk, (float*)khTh, 8192, 512, 512);
    gemm64<0, 4><<<dim3(128, 8), 256, 0, stream>>>(kvbuf, Wv, bv, (float*)vhh, 8192, 512, 512);
    gemm64<0, 0><<<dim3(8, 8), 256, 0, stream>>>(q_w, Wq, nullptr, Wqq, 512, 512, 512);
    bqq_kernel<<<2, 256, 0, stream>>>(q_b, Wq, bq, bqq);
    gemm64<0, 0><<<dim3(8, 64), 256, 0, stream>>>(Wo, syn_w, nullptr, W2, 512, 4096, 512);
    bias2_kernel<<<16, 256, 0, stream>>>(bo, syn_w, syn_b, bias2);
    wt_build<<<dim3(80, 128), 256, 0, stream>>>(W2, syn_w, WTh);
    conv_w1<<<6400, 256, 0, stream>>>(nlm_w1, w1h);
    act0_kernel<<<256, 256, 0, stream>>>(start_ac, acthist);

    float* out_sync = out + (size_t)BB * NOUT * TT + (size_t)BB * 2 * TT;

    static int lds_attr_set = 0;
    if (!lds_attr_set) {
        hipFuncSetAttribute(reinterpret_cast<const void*>(k_tick),
                            hipFuncAttributeMaxDynamicSharedMemorySize,
                            KT_LDS_FLOATS * 4);
        lds_attr_set = 1;
    }

    // ---- recurrent ticks: ONE launch each (2 internal grid barriers) ----
    for (int t = 0; t < TT; ++t) {
        int par = t & 1;
        const float* act_t = acthist + (size_t)t * (BB * DD);
        float* act_n = acthist + (size_t)(t + 1) * (BB * DD);
        k_tick<<<NBLKT, 256, KT_LDS_FLOATS * 4, stream>>>(
            act_t, act_n, idx_la, idx_ra, r_a,
            a_a + par * (BB * 512), b_a + par * (BB * 512),
            a_a + (par ^ 1) * (BB * 512), b_a + (par ^ 1) * (BB * 512),
            Wqq, bqq, khTh, vhh, WTh, bias2,
            ln_syn_g, ln_syn_b, trace,
            w1h, nlm_b1, nlm_w2, nlm_b2,
            obufR + (size_t)t * (BB * DIN),
            glR + (size_t)t * (DD * BB),
            partR + (size_t)t * (NBLKT * 64),
            bar, t);
    }

    // ---- deferred output path ----
    k_syncscan<<<64, 256, 0, stream>>>(acthist, idx_lo, idx_ro, r_o, a_o, b_o,
                                       so_hist, out_sync);
    pad_outw<<<2048, 256, 0, stream>>>(out_w, out_b, out_wp, out_bp);
    gemm64<0, 0><<<dim3(25, 16), 256, 0, stream>>>(so_hist, out_wp, out_bp, predt,
                                                   1600, 1024, 512);
    k6_cert<<<1600, 256, 0, stream>>>(predt, out);
}

// Round 13
// 4246.585 us; speedup vs baseline: 1.2522x; 1.2522x over previous
//
#include <hip/hip_runtime.h>
#include <math.h>

// Problem constants
#define BB 32
#define CC 512
#define SS 256      // kv tokens
#define DD 2048     // d_model
#define DIN 512
#define NH 8
#define DHD 64
#define TT 50
#define MM 25
#define HHID 16
#define NSA 512
#define NSO 512
#define NOUT 1000

// bf16 helpers (fp32 arithmetic everywhere; bf16 is storage-only)
__device__ __forceinline__ unsigned short f2bf(float f) {
    unsigned u = __float_as_uint(f);
    u += 0x7fffu + ((u >> 16) & 1u);      // round-to-nearest-even
    return (unsigned short)(u >> 16);
}
__device__ __forceinline__ float bf2f(unsigned short s) {
    return __uint_as_float((unsigned)s << 16);
}
__device__ __forceinline__ float blo(unsigned u) {
    return __uint_as_float(u << 16);
}
__device__ __forceinline__ float bhi(unsigned u) {
    return __uint_as_float(u & 0xffff0000u);
}

// ---------------------------------------------------------------------------
// Init: decays, sync states, trace0 (bf16)
// ---------------------------------------------------------------------------
__global__ void init_kernel(const float* __restrict__ dec_a, const float* __restrict__ dec_o,
                            const float* __restrict__ start_act, const float* __restrict__ start_trace,
                            const int* __restrict__ idx_lo, const int* __restrict__ idx_ro,
                            float* __restrict__ r_a, float* __restrict__ r_o,
                            float* __restrict__ a_a, float* __restrict__ b_a,
                            float* __restrict__ a_o, float* __restrict__ b_o,
                            unsigned short* __restrict__ trace)
{
    int i = blockIdx.x * 256 + threadIdx.x;
    if (i < 512) {
        r_a[i] = expf(-fminf(fmaxf(dec_a[i], 0.f), 15.f));
        r_o[i] = expf(-fminf(fmaxf(dec_o[i], 0.f), 15.f));
    }
    if (i < BB * NSA) {
        a_a[i] = 0.f; b_a[i] = 0.f;
        int j = i & 511;
        a_o[i] = start_act[idx_lo[j]] * start_act[idx_ro[j]];
        b_o[i] = 1.f;
    }
    if (i < BB * MM * DD) {
        int rem = i % (MM * DD);
        int m = rem / DD, d = rem % DD;
        trace[i] = f2bf(start_trace[d * MM + m]);   // start_trace is (D,M)
    }
}

// ---------------------------------------------------------------------------
// gemm64: generic 64x64 tiled GEMM (small/odd shapes). SMODE 0 only here.
// ---------------------------------------------------------------------------
__global__ void gemm64(const float* __restrict__ A, const float* __restrict__ Bm,
                       const float* __restrict__ bias, float* __restrict__ Cm,
                       int Mdim, int Ndim, int Kdim)
{
    __shared__ float As[16 * 65];
    __shared__ float Bs[16 * 64];
    int row0 = blockIdx.x * 64;
    int col0 = blockIdx.y * 64;
    int t = threadIdx.x;
    int tx = t & 15, ty = t >> 4;
    float acc[4][4] = {};
    for (int k0 = 0; k0 < Kdim; k0 += 16) {
        for (int i = t; i < 1024; i += 256) {
            int kk = i & 15, r = i >> 4;
            As[kk * 65 + r] = A[(size_t)(row0 + r) * Kdim + k0 + kk];
        }
        for (int i = t; i < 1024; i += 256) {
            int c = i & 63, kk = i >> 6;
            Bs[kk * 64 + c] = Bm[(size_t)(k0 + kk) * Ndim + col0 + c];
        }
        __syncthreads();
        #pragma unroll
        for (int kk = 0; kk < 16; ++kk) {
            float a[4], bb[4];
            #pragma unroll
            for (int i = 0; i < 4; i++) a[i] = As[kk * 65 + ty * 4 + i];
            #pragma unroll
            for (int j = 0; j < 4; j++) bb[j] = Bs[kk * 64 + tx * 4 + j];
            #pragma unroll
            for (int i = 0; i < 4; i++)
                #pragma unroll
                for (int j = 0; j < 4; j++) acc[i][j] += a[i] * bb[j];
        }
        __syncthreads();
    }
    #pragma unroll
    for (int i = 0; i < 4; i++)
        #pragma unroll
        for (int j = 0; j < 4; j++) {
            int row = row0 + ty * 4 + i, col = col0 + tx * 4 + j;
            Cm[(size_t)row * Ndim + col] = acc[i][j] + (bias ? bias[col] : 0.f);
        }
}

// ---------------------------------------------------------------------------
// gemm128: 128x64 tile, 8x4 per thread (32 FMA / 12 LDS floats). For the
// large precompute GEMMs. AMODE 0: row-major A. AMODE 1: A is x (B,C,S).
// SMODE 0: fp32 row-major + bias. SMODE 3: bf16 khT (B,H,DH,S).
// SMODE 4: bf16 vh (B,H,S,DH). Requires Mdim%128==0, Ndim%64==0, Kdim%16==0.
// ---------------------------------------------------------------------------
template<int AMODE, int SMODE>
__global__ __launch_bounds__(256) void gemm128(
    const float* __restrict__ A, const float* __restrict__ Bm,
    const float* __restrict__ bias, float* __restrict__ Cm,
    int Mdim, int Ndim, int Kdim)
{
    __shared__ float As[16 * 129];   // 8.3 KB
    __shared__ float Bs[16 * 64];    // 4.1 KB
    int row0 = blockIdx.x * 128;
    int col0 = blockIdx.y * 64;
    int t = threadIdx.x;
    int tx = t & 15, ty = t >> 4;    // 16 cols-groups x 16 row-groups(8 rows)
    float acc[8][4] = {};
    for (int k0 = 0; k0 < Kdim; k0 += 16) {
        if (AMODE == 0) {
            #pragma unroll
            for (int q = 0; q < 8; ++q) {
                int i = t + q * 256;            // 0..2047
                int kk = i & 15, r = i >> 4;
                As[kk * 129 + r] = A[(size_t)(row0 + r) * Kdim + k0 + kk];
            }
        } else {
            int b = row0 / SS, s0 = row0 % SS;  // row0%256==0 or 128; SS=256
            #pragma unroll
            for (int q = 0; q < 8; ++q) {
                int i = t + q * 256;
                int r = i & 127, kk = i >> 7;
                As[kk * 129 + r] = A[((size_t)b * CC + k0 + kk) * SS + s0 + r];
            }
        }
        #pragma unroll
        for (int q = 0; q < 4; ++q) {
            int i = t + q * 256;
            int c = i & 63, kk = i >> 6;
            Bs[kk * 64 + c] = Bm[(size_t)(k0 + kk) * Ndim + col0 + c];
        }
        __syncthreads();
        #pragma unroll
        for (int kk = 0; kk < 16; ++kk) {
            float a[8], bb[4];
            #pragma unroll
            for (int i = 0; i < 8; i++) a[i] = As[kk * 129 + ty * 8 + i];
            #pragma unroll
            for (int j = 0; j < 4; j++) bb[j] = Bs[kk * 64 + tx * 4 + j];
            #pragma unroll
            for (int i = 0; i < 8; i++)
                #pragma unroll
                for (int j = 0; j < 4; j++) acc[i][j] += a[i] * bb[j];
        }
        __syncthreads();
    }
    #pragma unroll
    for (int i = 0; i < 8; i++)
        #pragma unroll
        for (int j = 0; j < 4; j++) {
            int row = row0 + ty * 8 + i, col = col0 + tx * 4 + j;
            float v = acc[i][j] + (bias ? bias[col] : 0.f);
            if (SMODE == 0) {
                Cm[(size_t)row * Ndim + col] = v;
            } else if (SMODE == 3) {
                int b = row / SS, s = row % SS, h = col >> 6, dh = col & 63;
                ((unsigned short*)Cm)[(((size_t)b * NH + h) * DHD + dh) * SS + s] = f2bf(v);
            } else if (SMODE == 4) {
                int b = row / SS, s = row % SS, h = col >> 6, dh = col & 63;
                ((unsigned short*)Cm)[(((size_t)b * NH + h) * SS + s) * DHD + dh] = f2bf(v);
            }
        }
}

// LayerNorm over rows of 512 (in place)
__global__ void ln_rows(float* __restrict__ buf, const float* __restrict__ g,
                        const float* __restrict__ bta)
{
    int row = blockIdx.x, t = threadIdx.x;
    __shared__ float red[256];
    float v0 = buf[(size_t)row * 512 + t];
    float v1 = buf[(size_t)row * 512 + 256 + t];
    red[t] = v0 + v1; __syncthreads();
    for (int off = 128; off; off >>= 1) { if (t < off) red[t] += red[t + off]; __syncthreads(); }
    float mu = red[0] * (1.f / 512.f); __syncthreads();
    float d0 = v0 - mu, d1 = v1 - mu;
    red[t] = d0 * d0 + d1 * d1; __syncthreads();
    for (int off = 128; off; off >>= 1) { if (t < off) red[t] += red[t + off]; __syncthreads(); }
    float rstd = 1.f / sqrtf(red[0] * (1.f / 512.f) + 1e-5f);
    buf[(size_t)row * 512 + t]       = d0 * rstd * g[t] + bta[t];
    buf[(size_t)row * 512 + 256 + t] = d1 * rstd * g[t + 256] + bta[t + 256];
}

__global__ void bqq_kernel(const float* __restrict__ q_b, const float* __restrict__ Wq,
                           const float* __restrict__ bq, float* __restrict__ bqq)
{
    int c = blockIdx.x * 256 + threadIdx.x;
    if (c >= 512) return;
    float acc = bq[c];
    for (int k = 0; k < 512; k++) acc += q_b[k] * Wq[k * 512 + c];
    bqq[c] = acc;
}

__global__ void bias2_kernel(const float* __restrict__ bo, const float* __restrict__ syn_w,
                             const float* __restrict__ syn_b, float* __restrict__ bias2)
{
    int c = blockIdx.x * 256 + threadIdx.x;
    if (c >= 4096) return;
    float acc = syn_b[c];
    for (int k = 0; k < 512; k++) acc += bo[k] * syn_w[(size_t)k * 4096 + c];
    bias2[c] = acc;
}

// Build WTh[c][k] = bf16(Wcomb[k][c]) (Wcomb = [W2;syn_w]).
__global__ void wt_build(const float* __restrict__ W2, const float* __restrict__ syn_w,
                         unsigned short* __restrict__ WTh)
{
    __shared__ float tile[32][33];
    int k0 = blockIdx.x * 32, c0 = blockIdx.y * 32;
    int t = threadIdx.x;
    int col = t & 31, rq = t >> 5;
    #pragma unroll
    for (int q = 0; q < 4; ++q) {
        int kk = q * 8 + rq;
        int k = k0 + kk;
        const float* src = (k < 512 ? W2 : syn_w) + (size_t)k * 4096 + c0;
        tile[kk][col] = src[col];
    }
    __syncthreads();
    #pragma unroll
    for (int q = 0; q < 4; ++q) {
        int cc = q * 8 + rq;
        WTh[(size_t)(c0 + cc) * 2560 + k0 + col] = f2bf(tile[col][cc]);
    }
}

// Convert nlm_w1 to bf16.
__global__ void conv_w1(const float* __restrict__ w1, unsigned short* __restrict__ w1h)
{
    int i = blockIdx.x * 256 + threadIdx.x;
    if (i < 25 * 32 * DD) w1h[i] = f2bf(w1[i]);
}

__global__ void act0_kernel(const float* __restrict__ start_act, float* __restrict__ act0slot)
{
    int i = blockIdx.x * 256 + threadIdx.x;
    if (i < BB * DD) act0slot[i] = start_act[i & (DD - 1)];
}

__global__ void pad_outw(const float* __restrict__ out_w, const float* __restrict__ out_b,
                         float* __restrict__ out_wp, float* __restrict__ out_bp)
{
    int i = blockIdx.x * 256 + threadIdx.x;
    if (i < 512 * 1024) {
        int r = i >> 10, c = i & 1023;
        out_wp[i] = (c < 1000) ? out_w[r * 1000 + c] : 0.f;
    }
    if (i < 1024) out_bp[i] = (i < 1000) ? out_b[i] : 0.f;
}

// ---------------------------------------------------------------------------
// K1: sync_a + q-projection slice + attention (bf16 K/V). Block = (b,h).
// ---------------------------------------------------------------------------
__global__ __launch_bounds__(256) void k1_front(
    const float* __restrict__ act, const int* __restrict__ la, const int* __restrict__ ra,
    const float* __restrict__ r_a,
    const float* __restrict__ aold, const float* __restrict__ bold,
    float* __restrict__ anew, float* __restrict__ bnew,
    const float* __restrict__ Wqq, const float* __restrict__ bqq,
    const unsigned short* __restrict__ khTh, const unsigned short* __restrict__ vhh,
    float* __restrict__ obuf)
{
    __shared__ float sa[512];
    __shared__ float qp[256];
    __shared__ float qs[64];
    __shared__ float ps[256];
    __shared__ float red[256];
    int bh = blockIdx.x, b = bh >> 3, h = bh & 7;
    int tid = threadIdx.x;
    const float* actb = act + b * DD;
    for (int j = tid; j < 512; j += 256) {
        float p = actb[la[j]] * actb[ra[j]];
        float r = r_a[j];
        float aa = r * aold[b * 512 + j] + p;
        float bb = r * bold[b * 512 + j] + 1.f;
        sa[j] = aa / sqrtf(bb);
        if (h == 0) { anew[b * 512 + j] = aa; bnew[b * 512 + j] = bb; }
    }
    __syncthreads();
    {
        int cl = tid & 63, q = tid >> 6;
        const float* wcol = Wqq + h * 64 + cl;
        float acc = 0.f;
        #pragma unroll 8
        for (int k = q * 128; k < q * 128 + 128; ++k)
            acc += sa[k] * wcol[k * 512];
        qp[tid] = acc;
    }
    __syncthreads();
    if (tid < 64)
        qs[tid] = qp[tid] + qp[tid + 64] + qp[tid + 128] + qp[tid + 192] + bqq[h * 64 + tid];
    __syncthreads();
    const unsigned short* kb = khTh + (size_t)bh * 64 * 256;   // [dh][s]
    float sc = 0.f;
    #pragma unroll 8
    for (int dh = 0; dh < 64; ++dh) sc += qs[dh] * bf2f(kb[dh * 256 + tid]);
    sc *= 0.125f;
    red[tid] = sc; __syncthreads();
    for (int off = 128; off; off >>= 1) { if (tid < off) red[tid] = fmaxf(red[tid], red[tid + off]); __syncthreads(); }
    float mx = red[0]; __syncthreads();
    float e = expf(sc - mx);
    red[tid] = e; __syncthreads();
    for (int off = 128; off; off >>= 1) { if (tid < off) red[tid] += red[tid + off]; __syncthreads(); }
    float inv = 1.f / red[0];
    ps[tid] = e * inv;
    __syncthreads();
    int dh = tid & 63, ch = tid >> 6;
    const unsigned short* vb = vhh + (size_t)bh * 256 * 64;    // [s][dh]
    float acc = 0.f;
    for (int s = ch * 64; s < ch * 64 + 64; ++s) acc += ps[s] * bf2f(vb[s * 64 + dh]);
    red[tid] = acc; __syncthreads();
    if (tid < 128) red[tid] += red[tid + 128];
    __syncthreads();
    if (tid < 64) obuf[b * 512 + h * 64 + tid] = red[tid] + red[tid + 64];
}

// ---------------------------------------------------------------------------
// K2: full-K synapse GEMM (bf16 weights) + in-register GLU + LN partials.
// Grid 512: block = 4 col-pairs. Thread = kh*128 + cpair*32 + r.
// ---------------------------------------------------------------------------
__global__ __launch_bounds__(256) void k2_glu(
    const float* __restrict__ obuf, const float* __restrict__ act,
    const unsigned short* __restrict__ WTh, const float* __restrict__ bias2,
    float* __restrict__ glbufT, float* __restrict__ partials)
{
    __shared__ float As[2 * 32 * 160];   // 40 KB: [kh][row][160k], swizzled
    int tid = threadIdx.x, blk = blockIdx.x;
    int kh = tid >> 7;            // 0..1
    int cpair = (tid >> 5) & 3;   // 0..3
    int r = tid & 31;
    int c = blk * 4 + cpair;
    const unsigned short* wta = WTh + (size_t)c * 2560 + kh * 1280;
    const unsigned short* wtb = WTh + (size_t)(c + 2048) * 2560 + kh * 1280;
    float acc_a = 0.f, acc_b = 0.f;
    for (int ri = 0; ri < 8; ++ri) {
        __syncthreads();
        // stage both K-halves' 160-k chunks: 2*32*40 float4 = 2560, 10/thread
        #pragma unroll
        for (int q = 0; q < 10; ++q) {
            int i = tid + q * 256;        // 0..2559
            int hh = i / 1280;
            int rem = i - hh * 1280;
            int rr = rem / 40, kg = rem - (rem / 40) * 40;
            int k = hh * 1280 + ri * 160 + kg * 4;
            float4 v;
            if (k < 512) v = *(const float4*)(obuf + rr * 512 + k);
            else         v = *(const float4*)(act + rr * 2048 + (k - 512));
            *(float4*)(As + hh * 5120 + rr * 160 + ((kg ^ (rr & 7)) << 2)) = v;
        }
        __syncthreads();
        const float* Ar = As + kh * 5120 + r * 160;
        const unsigned short* wtaa = wta + ri * 160;
        const unsigned short* wtbb = wtb + ri * 160;
        int sw = r & 7;
        #pragma unroll 4
        for (int kc = 0; kc < 20; ++kc) {
            uint4 wa = *(const uint4*)(wtaa + kc * 8);   // 8 bf16 weights
            uint4 wb = *(const uint4*)(wtbb + kc * 8);
            float4 a0 = *(const float4*)(Ar + (((2 * kc) ^ sw) << 2));
            float4 a1 = *(const float4*)(Ar + (((2 * kc + 1) ^ sw) << 2));
            acc_a += a0.x * blo(wa.x) + a0.y * bhi(wa.x) + a0.z * blo(wa.y) + a0.w * bhi(wa.y)
                   + a1.x * blo(wa.z) + a1.y * bhi(wa.z) + a1.z * blo(wa.w) + a1.w * bhi(wa.w);
            acc_b += a0.x * blo(wb.x) + a0.y * bhi(wb.x) + a0.z * blo(wb.y) + a0.w * bhi(wb.y)
                   + a1.x * blo(wb.z) + a1.y * bhi(wb.z) + a1.z * blo(wb.w) + a1.w * bhi(wb.w);
        }
    }
    // combine K-halves through LDS (reuse As)
    __syncthreads();
    float* red_a = As;            // 128
    float* red_b = As + 128;      // 128
    float* gls   = As + 256;      // 128
    float* gl2s  = As + 384;      // 128
    if (kh == 1) {
        red_a[cpair * 32 + r] = acc_a;
        red_b[cpair * 32 + r] = acc_b;
    }
    __syncthreads();
    if (kh == 0) {
        float ua = acc_a + red_a[cpair * 32 + r] + bias2[c];
        float ub = acc_b + red_b[cpair * 32 + r] + bias2[c + 2048];
        float gl = ua * (1.f / (1.f + expf(-ub)));
        glbufT[c * 32 + r] = gl;
        gls[cpair * 32 + r] = gl;
        gl2s[cpair * 32 + r] = gl * gl;
    }
    __syncthreads();
    if (tid < 32) {
        float s = 0.f, s2 = 0.f;
        #pragma unroll
        for (int cp = 0; cp < 4; ++cp) { s += gls[cp * 32 + tid]; s2 += gl2s[cp * 32 + tid]; }
        partials[blk * 64 + tid * 2]     = s;
        partials[blk * 64 + tid * 2 + 1] = s2;
    }
}

// ---------------------------------------------------------------------------
// K4: LN-finish + per-neuron MLP with LDS-shared w1 (bf16 source, bf16 trace).
// Grid 512 = (dtile 0..127 -> 16 d's) x (bgrp 0..3 -> 8 b's).
// Thread = hh*128 + b_l*16 + d_l; halves exchanged via LDS.
// ---------------------------------------------------------------------------
#define K4_LDS_FLOATS (12800 + 2176 + 256 + 256 + 16)
__global__ __launch_bounds__(256) void k4_nlm(
    const float* __restrict__ glbufT, const float* __restrict__ partials,
    const float* __restrict__ g, const float* __restrict__ bta,
    unsigned short* __restrict__ trace,
    const unsigned short* __restrict__ w1h, const float* __restrict__ b1,
    const float* __restrict__ w2, const float* __restrict__ b2,
    float* __restrict__ actout, int t_iter)
{
    extern __shared__ float lds[];
    float* wlds  = lds;             // 12800: [m*32+h][16 d_l]
    float* cross = lds + 12800;     // 2176
    float* r1 = lds + 14976;        // 256
    float* r2 = lds + 15232;        // 256
    float* sm = lds + 15488;        // 16
    int tid = threadIdx.x, blk = blockIdx.x;
    int dtile = blk & 127, bgrp = blk >> 7;
    int d0 = dtile * 16, b0 = bgrp * 8;
    int hh = tid >> 7;
    int b_l = (tid >> 4) & 7;
    int d_l = tid & 15;
    int b = b0 + b_l, d = d0 + d_l;

    // stage w1 slice from bf16: 12800 floats, 50 per thread
    for (int q = 0; q < 50; ++q) {
        int i = tid + q * 256;
        wlds[i] = bf2f(w1h[(size_t)(i >> 4) * 2048 + d0 + (i & 15)]);
    }
    // LN stats
    {
        int bb = tid >> 5, j = tid & 31;
        int bstat = b0 + bb;
        float s = 0.f, s2 = 0.f;
        #pragma unroll
        for (int q = 0; q < 16; ++q) {
            int kblk = j + 32 * q;
            s  += partials[kblk * 64 + bstat * 2];
            s2 += partials[kblk * 64 + bstat * 2 + 1];
        }
        r1[tid] = s; r2[tid] = s2;
        __syncthreads();
        for (int off = 16; off; off >>= 1) {
            if (j < off) { r1[tid] += r1[tid + off]; r2[tid] += r2[tid + off]; }
            __syncthreads();
        }
        if (j == 0) {
            float mu = r1[tid] * (1.f / 2048.f);
            float var = r2[tid] * (1.f / 2048.f) - mu * mu;
            sm[bb * 2] = mu;
            sm[bb * 2 + 1] = 1.f / sqrtf(var + 1e-5f);
        }
        __syncthreads();
    }
    float mu = sm[b_l * 2], rstd = sm[b_l * 2 + 1];
    float gl = glbufT[d * 32 + b];
    float nv = (gl - mu) * rstd * g[d] + bta[d];
    int newrow = t_iter % MM;
    if (hh == 0) trace[((size_t)b * MM + newrow) * DD + d] = f2bf(nv);

    // per-neuron MLP: this thread's 16 h's (h = hh*16 + h')
    float hp[16];
    {
        const float* b1d = b1 + d * 32 + hh * 16;
        #pragma unroll
        for (int h = 0; h < 16; h++) hp[h] = b1d[h];
    }
    const unsigned short* trb = trace + (size_t)b * MM * DD + d;
    for (int m = 0; m < 24; m++) {
        int mph = (t_iter + 1 + m) % 25;
        float tv = bf2f(trb[(size_t)mph * DD]);
        const float* wm = wlds + (m * 32 + hh * 16) * 16 + d_l;
        #pragma unroll
        for (int h = 0; h < 16; h++) hp[h] += tv * wm[h * 16];
    }
    {
        const float* wm = wlds + (24 * 32 + hh * 16) * 16 + d_l;
        #pragma unroll
        for (int h = 0; h < 16; h++) hp[h] += nv * wm[h * 16];
    }
    if (hh == 1) {
        float* cx = cross + (b_l * 16 + d_l) * 17;
        #pragma unroll
        for (int h = 0; h < 16; h++) cx[h] = hp[h];
    }
    __syncthreads();
    if (hh == 0) {
        const float* cx = cross + (b_l * 16 + d_l) * 17;
        float o0 = b2[d * 2], o1 = b2[d * 2 + 1];
        #pragma unroll
        for (int h = 0; h < 16; h++) {
            float hv = hp[h] * (1.f / (1.f + expf(-cx[h])));
            o0 += hv * w2[((size_t)h * 2) * DD + d];
            o1 += hv * w2[((size_t)h * 2 + 1) * DD + d];
        }
        actout[b * DD + d] = o0 * (1.f / (1.f + expf(-o1)));
    }
}

// ---------------------------------------------------------------------------
// Post: sync_o linear recurrence over all 50 ticks. Thread = (b,j).
// ---------------------------------------------------------------------------
__global__ __launch_bounds__(256) void k_syncscan(
    const float* __restrict__ acthist, const int* __restrict__ lo, const int* __restrict__ ro,
    const float* __restrict__ r_o,
    const float* __restrict__ a_o0, const float* __restrict__ b_o0,
    float* __restrict__ so_hist, float* __restrict__ out_sync)
{
    int idx = blockIdx.x * 256 + threadIdx.x;   // 0..16383
    int b = idx >> 9, j = idx & 511;
    float aa = a_o0[idx], bb = b_o0[idx];
    float rr = r_o[j];
    int il = lo[j], ir = ro[j];
    const float* ah = acthist + (size_t)(BB * DD) + b * DD;
    float s = 0.f;
    for (int t = 0; t < TT; ++t) {
        float p = ah[il] * ah[ir];
        aa = rr * aa + p;
        bb = rr * bb + 1.f;
        s = aa / sqrtf(bb);
        so_hist[(size_t)t * (BB * 512) + idx] = s;
        ah += BB * DD;
    }
    out_sync[idx] = s;
}

// ---------------------------------------------------------------------------
// Post: certainty + prediction write-out for ALL ticks. Grid 1600 = (t, b).
// ---------------------------------------------------------------------------
__global__ __launch_bounds__(256) void k6_cert(
    const float* __restrict__ predt, float* __restrict__ d_out)
{
    int t_iter = blockIdx.x >> 5, b = blockIdx.x & 31, t = threadIdx.x;
    __shared__ float red[256];
    const float* pr = predt + ((size_t)t_iter * 32 + b) * 1024;
    float pv[4];
    float mx = -1e30f;
    #pragma unroll
    for (int ii = 0; ii < 4; ++ii) {
        int c = t + ii * 256;
        float v = -1e30f;
        if (c < 1000) {
            v = pr[c];
            d_out[(size_t)b * NOUT * TT + (size_t)c * TT + t_iter] = v;
        }
        pv[ii] = v;
        mx = fmaxf(mx, v);
    }
    red[t] = mx; __syncthreads();
    for (int off = 128; off; off >>= 1) { if (t < off) red[t] = fmaxf(red[t], red[t + off]); __syncthreads(); }
    mx = red[0]; __syncthreads();
    float s1 = 0.f, s2 = 0.f;
    #pragma unroll
    for (int ii = 0; ii < 4; ++ii) {
        int c = t + ii * 256;
        if (c < 1000) { float xx = pv[ii] - mx; float e = expf(xx); s1 += e; s2 += e * xx; }
    }
    red[t] = s1; __syncthreads();
    for (int off = 128; off; off >>= 1) { if (t < off) red[t] += red[t + off]; __syncthreads(); }
    s1 = red[0]; __syncthreads();
    red[t] = s2; __syncthreads();
    for (int off = 128; off; off >>= 1) { if (t < off) red[t] += red[t + off]; __syncthreads(); }
    s2 = red[0];
    if (t == 0) {
        float ne = -(s2 / s1 - logf(s1)) * (1.f / logf(1000.f));
        size_t base = (size_t)BB * NOUT * TT + (size_t)b * 2 * TT + t_iter;
        d_out[base] = ne;
        d_out[base + TT] = 1.f - ne;
    }
}

// ---------------------------------------------------------------------------
extern "C" void kernel_launch(void* const* d_in, const int* in_sizes, int n_in,
                              void* d_out, int out_size, void* d_ws, size_t ws_size,
                              hipStream_t stream)
{
    const float* x        = (const float*)d_in[0];
    const float* kv_w     = (const float*)d_in[1];
    const float* kv_b     = (const float*)d_in[2];
    const float* ln_kv_g  = (const float*)d_in[3];
    const float* ln_kv_b  = (const float*)d_in[4];
    const float* q_w      = (const float*)d_in[5];
    const float* q_b      = (const float*)d_in[6];
    const float* Wq       = (const float*)d_in[7];
    const float* bq       = (const float*)d_in[8];
    const float* Wk       = (const float*)d_in[9];
    const float* bk       = (const float*)d_in[10];
    const float* Wv       = (const float*)d_in[11];
    const float* bv       = (const float*)d_in[12];
    const float* Wo       = (const float*)d_in[13];
    const float* bo       = (const float*)d_in[14];
    const float* syn_w    = (const float*)d_in[15];
    const float* syn_b    = (const float*)d_in[16];
    const float* ln_syn_g = (const float*)d_in[17];
    const float* ln_syn_b = (const float*)d_in[18];
    const float* nlm_w1   = (const float*)d_in[19];
    const float* nlm_b1   = (const float*)d_in[20];
    const float* nlm_w2   = (const float*)d_in[21];
    const float* nlm_b2   = (const float*)d_in[22];
    const float* out_w    = (const float*)d_in[23];
    const float* out_b    = (const float*)d_in[24];
    const float* dec_a    = (const float*)d_in[25];
    const float* dec_o    = (const float*)d_in[26];
    const float* start_tr = (const float*)d_in[27];
    const float* start_ac = (const float*)d_in[28];
    const int*   idx_la   = (const int*)d_in[29];
    const int*   idx_ra   = (const int*)d_in[30];
    const int*   idx_lo   = (const int*)d_in[31];
    const int*   idx_ro   = (const int*)d_in[32];
    float* out = (float*)d_out;

    // workspace carve (floats). Post-loop aliases: acthist->kvbuf,
    // so_hist/predt->vhb-slot, out_wp/out_bp->khT-slot.
    float* w = (float*)d_ws;
    float* kvbuf = w;            w += (size_t)8192 * 512;     // acthist alias
    float* bigA  = w;            w += (size_t)8192 * 512;     // out_wp/bp post-loop
    float* bigB  = w;            w += (size_t)8192 * 512;     // so_hist/predt post-loop
    float* Wqq   = w;            w += (size_t)512 * 512;
    float* bqq   = w;            w += 512;
    float* W2    = w;            w += (size_t)512 * 4096;
    float* bias2 = w;            w += 4096;
    float* r_a   = w;            w += 512;
    float* r_o   = w;            w += 512;
    float* a_a   = w;            w += 2 * BB * NSA;           // ping-pong
    float* b_a   = w;            w += 2 * BB * NSA;
    float* a_o   = w;            w += BB * NSO;
    float* b_o   = w;            w += BB * NSO;
    float* obuf  = w;            w += BB * DIN;
    float* glbufT = w;           w += (size_t)DD * BB;        // [c][b]
    float* partials = w;         w += 512 * 32 * 2;           // [blk][b][2]
    unsigned short* trace = (unsigned short*)w;  w += (size_t)BB * MM * DD / 2;  // bf16
    unsigned short* WTh  = (unsigned short*)w;  w += (size_t)4096 * 2560 / 2;    // 21MB bf16
    unsigned short* khTh = (unsigned short*)w;  w += (size_t)8192 * 512 / 2;     // 8.4MB
    unsigned short* vhh  = (unsigned short*)w;  w += (size_t)8192 * 512 / 2;
    unsigned short* w1h  = (unsigned short*)w;  w += (size_t)25 * 32 * DD / 2;

    float* acthist = kvbuf;                 // 51*65536 = 3.34M <= 4.19M
    float* out_wp  = bigA;                  // 524,288 (post-loop)
    float* out_bp  = bigA + 524288;         // 1024
    float* so_hist = bigB;                  // 819,200 (post-loop)
    float* predt   = bigB + 819200;         // 1.64M (post-loop; total <= 4.19M)

    // ---- precompute ----
    init_kernel<<<6400, 256, 0, stream>>>(dec_a, dec_o, start_ac, start_tr, idx_lo, idx_ro,
                                          r_a, r_o, a_a, b_a, a_o, b_o, trace);
    gemm128<1, 0><<<dim3(64, 8), 256, 0, stream>>>(x, kv_w, kv_b, kvbuf, 8192, 512, 512);
    ln_rows<<<8192, 256, 0, stream>>>(kvbuf, ln_kv_g, ln_kv_b);
    gemm128<0, 3><<<dim3(64, 8), 256, 0, stream>>>(kvbuf, Wk, bk, (float*)khTh, 8192, 512, 512);
    gemm128<0, 4><<<dim3(64, 8), 256, 0, stream>>>(kvbuf, Wv, bv, (float*)vhh, 8192, 512, 512);
    gemm64<<<dim3(8, 8), 256, 0, stream>>>(q_w, Wq, nullptr, Wqq, 512, 512, 512);
    bqq_kernel<<<2, 256, 0, stream>>>(q_b, Wq, bq, bqq);
    gemm128<0, 0><<<dim3(4, 64), 256, 0, stream>>>(Wo, syn_w, nullptr, W2, 512, 4096, 512);
    bias2_kernel<<<16, 256, 0, stream>>>(bo, syn_w, syn_b, bias2);
    wt_build<<<dim3(80, 128), 256, 0, stream>>>(W2, syn_w, WTh);
    conv_w1<<<6400, 256, 0, stream>>>(nlm_w1, w1h);
    act0_kernel<<<256, 256, 0, stream>>>(start_ac, acthist);

    float* out_sync = out + (size_t)BB * NOUT * TT + (size_t)BB * 2 * TT;

    // k4_nlm needs ~62KB dynamic LDS
    static int lds_attr_set = 0;
    if (!lds_attr_set) {
        hipFuncSetAttribute(reinterpret_cast<const void*>(k4_nlm),
                            hipFuncAttributeMaxDynamicSharedMemorySize,
                            K4_LDS_FLOATS * 4);
        lds_attr_set = 1;
    }

    // ---- recurrent ticks: 3 dispatches each ----
    for (int t = 0; t < TT; ++t) {
        int par = t & 1;
        const float* act_t = acthist + (size_t)t * (BB * DD);
        float* act_n = acthist + (size_t)(t + 1) * (BB * DD);
        k1_front<<<256, 256, 0, stream>>>(act_t, idx_la, idx_ra, r_a,
                                          a_a + par * (BB * 512), b_a + par * (BB * 512),
                                          a_a + (par ^ 1) * (BB * 512), b_a + (par ^ 1) * (BB * 512),
                                          Wqq, bqq, khTh, vhh, obuf);
        k2_glu<<<512, 256, 0, stream>>>(obuf, act_t, WTh, bias2, glbufT, partials);
        k4_nlm<<<512, 256, K4_LDS_FLOATS * 4, stream>>>(glbufT, partials,
                                            ln_syn_g, ln_syn_b, trace,
                                            w1h, nlm_b1, nlm_w2, nlm_b2, act_n, t);
    }

    // ---- deferred output path ----
    k_syncscan<<<64, 256, 0, stream>>>(acthist, idx_lo, idx_ro, r_o, a_o, b_o,
                                       so_hist, out_sync);
    pad_outw<<<2048, 256, 0, stream>>>(out_w, out_b, out_wp, out_bp);
    gemm64<<<dim3(25, 16), 256, 0, stream>>>(so_hist, out_wp, out_bp, predt,
                                             1600, 1024, 512);
    k6_cert<<<1600, 256, 0, stream>>>(predt, out);
}